// Round 1
// baseline (219.436 us; speedup 1.0000x reference)
//
#include <hip/hip_runtime.h>
#include <math.h>

#define KW 5
#define PADK 2
#define BETA 15.0f
#define MSHIFT 3.0f
#define C_IN 8
#define C_OUT 8
#define HH 256
#define WW 256
#define TILE 32
#define TH 36  // TILE + KW - 1

__global__ __launch_bounds__(256, 3) void Morphology_kernel(
    const float* __restrict__ x, const float* __restrict__ wgt,
    float* __restrict__ out)
{
    __shared__ float ex[C_IN * TH * TH];  // 8*36*36*4 = 41472 B -> 3 blocks/CU

    const int tid = threadIdx.x;
    const int tx = tid & 31;
    const int ty = tid >> 5;       // 0..7
    const int w0 = blockIdx.x * TILE;
    const int h0 = blockIdx.y * TILE;
    const int b  = blockIdx.z;

    // Stage exp(beta*(x - M)) tile. Zero-padding -> exp(-beta*M) falls out of
    // the same formula with v=0, exactly matching the reference's jnp.pad(0).
    const int total = C_IN * TH * TH; // 10368
    for (int idx = tid; idx < total; idx += 256) {
        int c   = idx / (TH * TH);
        int rem = idx - c * (TH * TH);
        int r   = rem / TH;
        int col = rem - r * TH;
        int gh = h0 + r - PADK;
        int gw = w0 + col - PADK;
        float v = 0.0f;
        if ((unsigned)gh < (unsigned)HH && (unsigned)gw < (unsigned)WW)
            v = x[((b * C_IN + c) * HH + gh) * WW + gw];
        ex[idx] = __expf(BETA * (v - MSHIFT));
    }
    __syncthreads();

    float acc[C_OUT][4];
    #pragma unroll
    for (int o = 0; o < C_OUT; ++o)
        #pragma unroll
        for (int i = 0; i < 4; ++i) acc[o][i] = 0.0f;

    // Exp-space 5x5 correlation: acc[o][i] = sum_c sum_tap ex * exp(beta*w)
    // (we fold exp(beta*w) on the fly? No — weight must be exp'd too; do it
    //  via uniform scalar math: wv_e = __expf(BETA*wv). 200 uniform exps per
    //  c-loop iter are scalar-uniform values; cost is negligible vs 6400 FMA.)
    for (int c = 0; c < C_IN; ++c) {
        #pragma unroll
        for (int dr = 0; dr < KW; ++dr) {
            float xv[4][KW];
            #pragma unroll
            for (int i = 0; i < 4; ++i) {
                int r = ty + 8 * i + dr;
                const float* row = &ex[c * (TH * TH) + r * TH + tx];
                #pragma unroll
                for (int dc = 0; dc < KW; ++dc) xv[i][dc] = row[dc];
            }
            #pragma unroll
            for (int dc = 0; dc < KW; ++dc) {
                #pragma unroll
                for (int o = 0; o < C_OUT; ++o) {
                    // uniform address -> s_load; uniform exp
                    float wv = wgt[(((o * C_IN + c) * KW + dr) * KW) + dc];
                    float wv_e = __expf(BETA * wv);
                    #pragma unroll
                    for (int i = 0; i < 4; ++i)
                        acc[o][i] = fmaf(xv[i][dc], wv_e, acc[o][i]);
                }
            }
        }
    }

    const float inv_beta = 1.0f / BETA;
    #pragma unroll
    for (int o = 0; o < C_OUT; ++o) {
        #pragma unroll
        for (int i = 0; i < 4; ++i) {
            int h = h0 + ty + 8 * i;
            out[((b * C_OUT + o) * HH + h) * WW + w0 + tx] =
                MSHIFT + __logf(acc[o][i]) * inv_beta;
        }
    }
}

extern "C" void kernel_launch(void* const* d_in, const int* in_sizes, int n_in,
                              void* d_out, int out_size, void* d_ws, size_t ws_size,
                              hipStream_t stream) {
    const float* x   = (const float*)d_in[0];
    const float* wgt = (const float*)d_in[1];
    float* out = (float*)d_out;

    const int B = in_sizes[0] / (C_IN * HH * WW);  // 16
    dim3 grid(WW / TILE, HH / TILE, B);            // (8, 8, 16) = 1024 blocks
    Morphology_kernel<<<grid, dim3(256), 0, stream>>>(x, wgt, out);
}

// Round 2
// 127.788 us; speedup vs baseline: 1.7172x; 1.7172x over previous
//
#include <hip/hip_runtime.h>
#include <math.h>

#define KW 5
#define BETA 15.0f
#define MSHIFT 3.0f
#define CIN 8
#define COUT 8
#define HH 256
#define WW 256
#define TW 64     // tile width
#define THT 16    // tile height
#define CW 68     // TW + 4 (halo)
#define CH 20     // THT + 4 (halo)
#define CG 4      // channels staged per group
#define NW (COUT*CIN*KW*KW)  // 1600 weights

__global__ void expw_kernel(const float* __restrict__ wgt,
                            float* __restrict__ expw) {
    int i = blockIdx.x * 256 + threadIdx.x;
    if (i < NW) expw[i] = __expf(BETA * wgt[i]);
}

// USE_WS: weights come from precomputed global table via uniform s_load.
// Fallback (!USE_WS, only if ws too small): per-block LDS weight table.
template<bool USE_WS>
__global__ __launch_bounds__(256, 4) void morph_kernel(
    const float* __restrict__ x, const float* __restrict__ wraw,
    const float* __restrict__ expw, float* __restrict__ out)
{
    __shared__ float exs[CG * CH * CW];  // 21760 B
    __shared__ float wl[NW];             // 6400 B (fallback; total 28160 B -> 4 blk/CU)

    const int tid = threadIdx.x;
    const int tx = tid & 63;   // column within tile; one wave = one ty slice
    const int ty = tid >> 6;   // 0..3, owns output rows 4*ty .. 4*ty+3

    // XCD-aware swizzle: dispatch round-robins lid%8 across XCDs; give XCD k
    // a contiguous (b, h_tile, w_tile) range so halo reads and row writes
    // merge in one L2. 1024 blocks = 16 b * 16 h * 4 w.
    const int lid = blockIdx.x;
    const int sw = (lid & 7) * 128 + (lid >> 3);
    const int b  = sw >> 6;
    const int t  = sw & 63;
    const int h0 = (t >> 2) * THT;
    const int w0 = (t & 3) * TW;

    if constexpr (!USE_WS) {
        for (int i = tid; i < NW; i += 256)
            wl[i] = __expf(BETA * wraw[i]);
    }

    float acc[COUT][4];
    #pragma unroll
    for (int o = 0; o < COUT; ++o)
        #pragma unroll
        for (int i = 0; i < 4; ++i) acc[o][i] = 0.0f;

    for (int g = 0; g < 2; ++g) {
        if (g) __syncthreads();  // prev group's readers done before overwrite
        // Stage exp(beta*(x - M)) for channels g*4..g*4+3 (zero-pad -> v=0).
        for (int idx = tid; idx < CG * CH * CW; idx += 256) {
            int cc  = idx / (CH * CW);
            int rem = idx - cc * (CH * CW);
            int rr  = rem / CW;
            int col = rem - rr * CW;
            int gh = h0 + rr - 2;
            int gw = w0 + col - 2;
            float v = 0.0f;
            if ((unsigned)gh < (unsigned)HH && (unsigned)gw < (unsigned)WW)
                v = x[((b * CIN + g * CG + cc) * HH + gh) * WW + gw];
            exs[idx] = __expf(BETA * (v - MSHIFT));
        }
        __syncthreads();

        for (int cc = 0; cc < CG; ++cc) {
            const int c = g * CG + cc;
            // 8 staged rows x 5 cols feed 4 output rows x 25 taps x 8 o.
            float xv[8][KW];
            #pragma unroll
            for (int rr = 0; rr < 8; ++rr)
                #pragma unroll
                for (int dc = 0; dc < KW; ++dc)
                    xv[rr][dc] = exs[cc * (CH * CW) + (ty * 4 + rr) * CW + tx + dc];
            #pragma unroll
            for (int o = 0; o < COUT; ++o) {
                const int wb = (o * CIN + c) * (KW * KW);
                #pragma unroll
                for (int j = 0; j < KW; ++j)
                    #pragma unroll
                    for (int dc = 0; dc < KW; ++dc) {
                        float wv;
                        if constexpr (USE_WS)
                            wv = expw[wb + j * KW + dc];  // uniform -> s_load
                        else
                            wv = wl[wb + j * KW + dc];
                        #pragma unroll
                        for (int i = 0; i < 4; ++i)
                            acc[o][i] = fmaf(xv[i + j][dc], wv, acc[o][i]);
                    }
            }
        }
    }

    const float inv_beta = 1.0f / BETA;
    #pragma unroll
    for (int o = 0; o < COUT; ++o)
        #pragma unroll
        for (int i = 0; i < 4; ++i) {
            int h = h0 + ty * 4 + i;
            out[((b * COUT + o) * HH + h) * WW + w0 + tx] =
                MSHIFT + __logf(acc[o][i]) * inv_beta;
        }
}

extern "C" void kernel_launch(void* const* d_in, const int* in_sizes, int n_in,
                              void* d_out, int out_size, void* d_ws, size_t ws_size,
                              hipStream_t stream) {
    const float* x   = (const float*)d_in[0];
    const float* wgt = (const float*)d_in[1];
    float* out  = (float*)d_out;
    float* expw = (float*)d_ws;

    const int B = in_sizes[0] / (CIN * HH * WW);  // 16
    const int nblk = B * (HH / THT) * (WW / TW);  // 1024

    if (ws_size >= NW * sizeof(float)) {
        expw_kernel<<<(NW + 255) / 256, 256, 0, stream>>>(wgt, expw);
        morph_kernel<true><<<nblk, 256, 0, stream>>>(x, wgt, expw, out);
    } else {
        morph_kernel<false><<<nblk, 256, 0, stream>>>(x, wgt, wgt, out);
    }
}

// Round 3
// 111.141 us; speedup vs baseline: 1.9744x; 1.1498x over previous
//
#include <hip/hip_runtime.h>
#include <math.h>

#define KW 5
#define BETA 15.0f
#define MSHIFT 3.0f
#define CIN 8
#define COUT 8
#define HH 256
#define WW 256
#define TW 64      // tile width  (4 groups of 16 px)
#define THT 16     // tile height
#define CWp 68     // TW + 4 halo
#define CHp 20     // THT + 4 halo

typedef float f32x4 __attribute__((ext_vector_type(4)));
typedef short s16x8 __attribute__((ext_vector_type(8)));

static __device__ __forceinline__ short f2bf(float f) {
    unsigned u = __float_as_uint(f);
    unsigned r = (u + 0x7FFFu + ((u >> 16) & 1u)) >> 16;  // RNE
    return (short)r;
}

// Exp-space 5x5 conv as implicit GEMM on matrix cores.
// k = tap*8 + c (tap = ki*5+kj, 25 real taps padded to 28 = 7 K32-steps).
// A (M=16 rows = o, 8 used)  : W'[o][k] = exp(beta*w), preloaded VGPR frags.
// B (N=16 cols = px)         : EX[k][px] from LDS, channel-fastest bf16 so one
//                              k-quad run (8 c = 16 B) is a single ds_read_b128.
// D: col=lane&15=px, row=quad*4+reg=o (quads 0,1 used).
__global__ __launch_bounds__(256, 4) void morph_mfma(
    const float* __restrict__ x, const float* __restrict__ wgt,
    float* __restrict__ out)
{
    __shared__ int4 exs[CHp * CWp];  // 21760 B: [r][col] -> 8 bf16 channels

    const int tid  = threadIdx.x;
    const int lane = tid & 63;
    const int wv   = tid >> 6;     // wave 0..3 -> output rows wv*4..wv*4+3
    const int px   = lane & 15;
    const int quad = lane >> 4;

    // XCD-contiguous swizzle: 1024 blocks = 8 XCD * 128; XCD k gets 2 batches.
    const int lid = blockIdx.x;
    const int sw  = (lid & 7) * 128 + (lid >> 3);
    const int b   = sw >> 6;
    const int t   = sw & 63;                  // 16 h-tiles * 4 w-tiles
    const int h0  = (t >> 2) * THT;
    const int w0  = (t & 3) * TW;

    // ---- A fragments (weights) + per-lane tap offsets, once per block ----
    s16x8 afrag[7];
    int   toff[7];
    #pragma unroll
    for (int g = 0; g < 7; ++g) {
        int tap = g * 4 + quad;
        int tc  = tap < 25 ? tap : 24;        // clamp addr; A=0 kills pad taps
        toff[g] = (tc / KW) * CWp + (tc % KW);
        s16x8 af;
        #pragma unroll
        for (int j = 0; j < 8; ++j) {         // j = c
            float v = 0.0f;
            if (tap < 25 && px < COUT)
                v = __expf(BETA * wgt[(px * CIN + j) * (KW * KW) + tap]);
            af[j] = f2bf(v);
        }
        afrag[g] = af;
    }

    // ---- stage exp(beta*(x-M)) halo tile, bf16 channel-fastest ----
    for (int s = tid; s < CHp * CWp; s += 256) {
        int r = s / CWp, col = s - r * CWp;
        int gh = h0 + r - 2, gw = w0 + col - 2;
        bool ok = ((unsigned)gh < (unsigned)HH) & ((unsigned)gw < (unsigned)WW);
        unsigned pk[4];
        #pragma unroll
        for (int c2 = 0; c2 < 4; ++c2) {
            float v0 = 0.0f, v1 = 0.0f;
            if (ok) {
                v0 = x[((b * CIN + 2 * c2) * HH + gh) * WW + gw];
                v1 = x[((b * CIN + 2 * c2 + 1) * HH + gh) * WW + gw];
            }
            unsigned lo = (unsigned short)f2bf(__expf(BETA * (v0 - MSHIFT)));
            unsigned hi = (unsigned short)f2bf(__expf(BETA * (v1 - MSHIFT)));
            pk[c2] = lo | (hi << 16);
        }
        int4 p; p.x = pk[0]; p.y = pk[1]; p.z = pk[2]; p.w = pk[3];
        exs[s] = p;  // lanes contiguous -> conflict-free ds_write_b128
    }
    __syncthreads();

    // ---- main: 16 px-groups per wave, 7 MFMA each (K=224 complete) ----
    const float inv_beta = 1.0f / BETA;
    for (int wb = 0; wb < 4; ++wb) {
        #pragma unroll
        for (int hl = 0; hl < 4; ++hl) {
            const int hh   = wv * 4 + hl;
            const int base = hh * CWp + wb * 16 + px;
            f32x4 acc = {0.0f, 0.0f, 0.0f, 0.0f};
            #pragma unroll
            for (int g = 0; g < 7; ++g) {
                s16x8 bfr = *(const s16x8*)&exs[base + toff[g]];
                acc = __builtin_amdgcn_mfma_f32_16x16x32_bf16(
                          afrag[g], bfr, acc, 0, 0, 0);
            }
            if (quad < 2) {
                #pragma unroll
                for (int r = 0; r < 4; ++r) {
                    int o = quad * 4 + r;
                    out[((b * COUT + o) * HH + h0 + hh) * WW + w0 + wb * 16 + px]
                        = MSHIFT + __logf(acc[r]) * inv_beta;
                }
            }
        }
    }
}

extern "C" void kernel_launch(void* const* d_in, const int* in_sizes, int n_in,
                              void* d_out, int out_size, void* d_ws, size_t ws_size,
                              hipStream_t stream) {
    const float* x   = (const float*)d_in[0];
    const float* wgt = (const float*)d_in[1];
    float* out = (float*)d_out;

    const int B = in_sizes[0] / (CIN * HH * WW);          // 16
    const int nblk = B * (HH / THT) * (WW / TW);          // 1024
    morph_mfma<<<nblk, 256, 0, stream>>>(x, wgt, out);
}